// Round 7
// baseline (136.003 us; speedup 1.0000x reference)
//
#include <hip/hip_runtime.h>

// affine_grid + grid_sample (bilinear, zeros, align_corners=False)
// N=64, C=3, H=345, W=456, fp32.
// Round 7: per-block tile loop with async-stage split (load-early / write-late).
constexpr int N_ = 64, C_ = 3, H_ = 345, W_ = 456;
constexpr int HW_ = H_ * W_;

constexpr int TW = 32, TH = 16;                // output tile: 512 px, 2 px/thread
constexpr int TX = 15, TY = 22;                // ceil(456/32), ceil(345/16)
constexpr int QS = 4;                          // ty quarters per (n,tx) column
constexpr int CCAP = 52;                       // staged cols (13 float4), LDS row stride
constexpr int RCAP = 28;                       // staged rows
constexpr int CJ   = 13;                       // float4 columns
constexpr int CH_STRIDE = RCAP * CCAP;         // 1456 floats/channel (17472 B total)

__device__ __forceinline__ void make_win(
    int w0, int h0, float Ax, float Bx, float Cx, float Ay, float By, float Cy,
    int& xa_out, int& ylo_out)
{
    float ws = (float)w0, we = (float)min(w0 + TW - 1, W_ - 1);
    float hs = (float)h0, he = (float)min(h0 + TH - 1, H_ - 1);
    float xw0 = ws * Ax, xw1 = we * Ax;
    float xh0 = hs * Bx, xh1 = he * Bx;
    float minix = Cx + fminf(xw0, xw1) + fminf(xh0, xh1);
    float maxix = Cx + fmaxf(xw0, xw1) + fmaxf(xh0, xh1);
    float yw0 = ws * Ay, yw1 = we * Ay;
    float yh0 = hs * By, yh1 = he * By;
    float miniy = Cy + fminf(yw0, yw1) + fminf(yh0, yh1);
    float maxiy = Cy + fmaxf(yw0, yw1) + fmaxf(yh0, yh1);

    int x_lo = (int)floorf(minix) - 1, x_hi = (int)floorf(maxix) + 2;
    int y_lo = (int)floorf(miniy) - 1, y_hi = (int)floorf(maxiy) + 2;

    int xa = x_lo & ~3;                        // align down (ok for negatives)
    int cols4 = (x_hi - xa + 4) >> 2;
    if (cols4 > CJ) xa += ((cols4 - CJ) >> 1) << 2;   // center oversized window
    int rows = y_hi - y_lo + 1;
    if (rows > RCAP) y_lo += (rows - RCAP) >> 1;

    xa_out = xa; ylo_out = y_lo;
}

__device__ __forceinline__ void stage_load(
    const float* __restrict__ xn, int xa, int ylo, int j, int rt, bool lo2,
    float4& s00, float4& s01, float4& s10, float4& s11, float4& s20, float4& s21)
{
    if (j >= CJ) return;
    int y0 = ylo + rt;
    bool interior = (xa >= 0) && (xa + CCAP <= W_) && (ylo >= 0) && (ylo + RCAP <= H_);
    if (interior) {
        const float* p0 = xn + (size_t)y0 * W_ + xa + 4 * j;
        s00 = *(const float4*)(p0);
        s10 = *(const float4*)(p0 + HW_);
        s20 = *(const float4*)(p0 + 2 * HW_);
        if (lo2) {
            const float* p1 = p0 + 16 * W_;
            s01 = *(const float4*)(p1);
            s11 = *(const float4*)(p1 + HW_);
            s21 = *(const float4*)(p1 + 2 * HW_);
        }
    } else {
        int xc = xa + 4 * j;
        bool ok0 = (unsigned)(xc + 0) < (unsigned)W_;
        bool ok1 = (unsigned)(xc + 1) < (unsigned)W_;
        bool ok2 = (unsigned)(xc + 2) < (unsigned)W_;
        bool ok3 = (unsigned)(xc + 3) < (unsigned)W_;
        auto ld = [&](const float* src, int y) -> float4 {
            bool yok = (unsigned)y < (unsigned)H_;
            const float* row = src + (size_t)y * W_ + xc;
            float4 v;
            v.x = (yok && ok0) ? row[0] : 0.0f;
            v.y = (yok && ok1) ? row[1] : 0.0f;
            v.z = (yok && ok2) ? row[2] : 0.0f;
            v.w = (yok && ok3) ? row[3] : 0.0f;
            return v;
        };
        s00 = ld(xn, y0);
        s10 = ld(xn + HW_, y0);
        s20 = ld(xn + 2 * HW_, y0);
        if (lo2) {
            int y1 = y0 + 16;
            s01 = ld(xn, y1);
            s11 = ld(xn + HW_, y1);
            s21 = ld(xn + 2 * HW_, y1);
        }
    }
}

__device__ __forceinline__ void stage_write(
    float* lds, int j, int rt, bool lo2,
    const float4& s00, const float4& s01, const float4& s10,
    const float4& s11, const float4& s20, const float4& s21)
{
    if (j >= CJ) return;
    float* d0 = lds + rt * CCAP + 4 * j;
    *(float4*)(d0)                 = s00;
    *(float4*)(d0 + CH_STRIDE)     = s10;
    *(float4*)(d0 + 2 * CH_STRIDE) = s20;
    if (lo2) {
        float* d1 = d0 + 16 * CCAP;
        *(float4*)(d1)                 = s01;
        *(float4*)(d1 + CH_STRIDE)     = s11;
        *(float4*)(d1 + 2 * CH_STRIDE) = s21;
    }
}

__global__ __launch_bounds__(256, 8) void gs_tiled(
    const float* __restrict__ x,      // [N,3,H,W]
    const float* __restrict__ theta,  // [N,2,3]
    float* __restrict__ out)          // [N,3,H,W]
{
    __shared__ float lds[3 * CH_STRIDE];

    // XCD-affine: batch n -> XCD n%8 only. 3840 blocks = 8 xcd x 8 bg x (15 tx x 4 q).
    int b    = blockIdx.x;
    int xcd  = b & 7;
    int i    = b >> 3;                 // 0..479
    int bg   = i / (TX * QS);          // 0..7
    int rem  = i - bg * (TX * QS);     // 0..59
    int tx   = rem >> 2;               // 0..14
    int q    = rem & 3;                // 0..3
    int n    = xcd + 8 * bg;
    int ty0  = (q * TY) >> 2;          // {0,5,11,16}
    int ty1  = ((q + 1) * TY) >> 2;    // {5,11,16,22}
    int w0   = tx * TW;

    const float* t = theta + n * 6;
    float t00 = t[0], t01 = t[1], t02 = t[2];
    float t10 = t[3], t11 = t[4], t12 = t[5];

    const float halfW = 0.5f * (float)W_, cW = 0.5f * (float)(W_ - 1);
    const float halfH = 0.5f * (float)H_, cH = 0.5f * (float)(H_ - 1);
    const float startx = -(1.0f - 1.0f / (float)W_);
    const float starty = -(1.0f - 1.0f / (float)H_);

    // Linear map: ix = Ax*w + Bx*h + Cx ; iy = Ay*w + By*h + Cy
    float Ax = t00;
    float Bx = t01 * ((float)W_ / (float)H_);
    float Cx = fmaf(startx, t00, fmaf(starty, t01, t02)) * halfW + cW;
    float Ay = t10 * ((float)H_ / (float)W_);
    float By = t11;
    float Cy = fmaf(startx, t10, fmaf(starty, t11, t12)) * halfH + cH;

    const float* xn = x + (size_t)n * 3 * HW_;
    float* on = out + (size_t)n * 3 * HW_;

    int tid = threadIdx.x;
    int j  = tid & 15, rt = tid >> 4;
    bool lo2 = rt < 12;
    int tw = (tid & 15) * 2, th = tid >> 4;

    float4 s00 = {}, s01 = {}, s10 = {}, s11 = {}, s20 = {}, s21 = {};

    // prologue: stage first tile (latency exposed once per block)
    int cxa, cylo;
    make_win(w0, ty0 * TH, Ax, Bx, Cx, Ay, By, Cy, cxa, cylo);
    stage_load(xn, cxa, cylo, j, rt, lo2, s00, s01, s10, s11, s20, s21);
    stage_write(lds, j, rt, lo2, s00, s01, s10, s11, s20, s21);
    __syncthreads();

    for (int k = ty0; k < ty1; ++k) {
        bool hn = (k + 1) < ty1;
        int nxa = 0, nylo = 0;
        if (hn) {
            make_win(w0, (k + 1) * TH, Ax, Bx, Cx, Ay, By, Cy, nxa, nylo);
            stage_load(xn, nxa, nylo, j, rt, lo2, s00, s01, s10, s11, s20, s21);
        }

        // ---- compute tile k from LDS (2 consecutive-w px/thread) ----
        int h = k * TH + th;
        int w = w0 + tw;
        if (w < W_ && h < H_) {
            float fw = (float)w, fh = (float)h;
            float hx  = fmaf(fh, Bx, Cx), hy = fmaf(fh, By, Cy);
            float ixA = fmaf(fw, Ax, hx), iyA = fmaf(fw, Ay, hy);
            float ixB = ixA + Ax,         iyB = iyA + Ay;

            float xfA = floorf(ixA), yfA = floorf(iyA);
            float fxA = ixA - xfA,   fyA = iyA - yfA;
            int   XA  = (int)xfA,    YA  = (int)yfA;

            float xfB = floorf(ixB), yfB = floorf(iyB);
            float fxB = ixB - xfB,   fyB = iyB - yfB;
            int   XB  = (int)xfB,    YB  = (int)yfB;

            int lcA = XA - cxa, lrA = YA - cylo;
            int lcB = XB - cxa, lrB = YB - cylo;
            bool inA = (unsigned)lcA < (unsigned)(CCAP - 1) && (unsigned)lrA < (unsigned)(RCAP - 1);
            bool inB = (unsigned)lcB < (unsigned)(CCAP - 1) && (unsigned)lrB < (unsigned)(RCAP - 1);

            float vA0, vA1, vA2, vB0, vB1, vB2;

            if (__builtin_expect(inA & inB, 1)) {
                const float* pA = &lds[lrA * CCAP + lcA];
                const float* pB = &lds[lrB * CCAP + lcB];
                {
                    float a00 = pA[0], a10 = pA[1], a01 = pA[CCAP], a11 = pA[CCAP + 1];
                    float b00 = pB[0], b10 = pB[1], b01 = pB[CCAP], b11 = pB[CCAP + 1];
                    float at = fmaf(fxA, a10 - a00, a00), ab = fmaf(fxA, a11 - a01, a01);
                    float bt = fmaf(fxB, b10 - b00, b00), bb = fmaf(fxB, b11 - b01, b01);
                    vA0 = fmaf(fyA, ab - at, at);
                    vB0 = fmaf(fyB, bb - bt, bt);
                }
                {
                    float a00 = pA[CH_STRIDE], a10 = pA[CH_STRIDE + 1];
                    float a01 = pA[CH_STRIDE + CCAP], a11 = pA[CH_STRIDE + CCAP + 1];
                    float b00 = pB[CH_STRIDE], b10 = pB[CH_STRIDE + 1];
                    float b01 = pB[CH_STRIDE + CCAP], b11 = pB[CH_STRIDE + CCAP + 1];
                    float at = fmaf(fxA, a10 - a00, a00), ab = fmaf(fxA, a11 - a01, a01);
                    float bt = fmaf(fxB, b10 - b00, b00), bb = fmaf(fxB, b11 - b01, b01);
                    vA1 = fmaf(fyA, ab - at, at);
                    vB1 = fmaf(fyB, bb - bt, bt);
                }
                {
                    float a00 = pA[2 * CH_STRIDE], a10 = pA[2 * CH_STRIDE + 1];
                    float a01 = pA[2 * CH_STRIDE + CCAP], a11 = pA[2 * CH_STRIDE + CCAP + 1];
                    float b00 = pB[2 * CH_STRIDE], b10 = pB[2 * CH_STRIDE + 1];
                    float b01 = pB[2 * CH_STRIDE + CCAP], b11 = pB[2 * CH_STRIDE + CCAP + 1];
                    float at = fmaf(fxA, a10 - a00, a00), ab = fmaf(fxA, a11 - a01, a01);
                    float bt = fmaf(fxB, b10 - b00, b00), bb = fmaf(fxB, b11 - b01, b01);
                    vA2 = fmaf(fyA, ab - at, at);
                    vB2 = fmaf(fyB, bb - bt, bt);
                }
            } else {
                // rare: corner(s) outside staged window -> direct global gather
                float gxA = 1.0f - fxA, gyA = 1.0f - fyA;
                float gxB = 1.0f - fxB, gyB = 1.0f - fyB;
                float wA00 = gxA * gyA, wA10 = fxA * gyA, wA01 = gxA * fyA, wA11 = fxA * fyA;
                float wB00 = gxB * gyB, wB10 = fxB * gyB, wB01 = gxB * fyB, wB11 = fxB * fyB;
                vA0 = vA1 = vA2 = vB0 = vB1 = vB2 = 0.0f;
#define CORNG(xi, yi, wt, d0, d1, d2)                                         \
                if ((unsigned)(xi) < (unsigned)W_ && (unsigned)(yi) < (unsigned)H_) { \
                    int off = (yi) * W_ + (xi);                               \
                    d0 += xn[off] * (wt);                                     \
                    d1 += xn[HW_ + off] * (wt);                               \
                    d2 += xn[2 * HW_ + off] * (wt);                           \
                }
                CORNG(XA,     YA,     wA00, vA0, vA1, vA2)
                CORNG(XA + 1, YA,     wA10, vA0, vA1, vA2)
                CORNG(XA,     YA + 1, wA01, vA0, vA1, vA2)
                CORNG(XA + 1, YA + 1, wA11, vA0, vA1, vA2)
                CORNG(XB,     YB,     wB00, vB0, vB1, vB2)
                CORNG(XB + 1, YB,     wB10, vB0, vB1, vB2)
                CORNG(XB,     YB + 1, wB01, vB0, vB1, vB2)
                CORNG(XB + 1, YB + 1, wB11, vB0, vB1, vB2)
#undef CORNG
            }

            size_t o = (size_t)h * W_ + w;
            *(float2*)(on + o)           = make_float2(vA0, vB0);
            *(float2*)(on + o + HW_)     = make_float2(vA1, vB1);
            *(float2*)(on + o + 2 * HW_) = make_float2(vA2, vB2);
        }

        __syncthreads();                       // all LDS reads of tile k done
        if (hn) {
            stage_write(lds, j, rt, lo2, s00, s01, s10, s11, s20, s21);  // vmcnt hidden under compute
            cxa = nxa; cylo = nylo;
        }
        __syncthreads();                       // LDS of tile k+1 ready
    }
}

extern "C" void kernel_launch(void* const* d_in, const int* in_sizes, int n_in,
                              void* d_out, int out_size, void* d_ws, size_t ws_size,
                              hipStream_t stream) {
    const float* x     = (const float*)d_in[0];
    const float* theta = (const float*)d_in[1];
    float* out = (float*)d_out;

    int blocks = N_ * TX * QS;   // 3840, divisible by 8
    gs_tiled<<<blocks, 256, 0, stream>>>(x, theta, out);
}

// Round 8
// 54.447 us; speedup vs baseline: 2.4979x; 2.4979x over previous
//
#include <hip/hip_runtime.h>

// affine_grid + grid_sample (bilinear, zeros, align_corners=False)
// N=64, C=3, H=345, W=456, fp32.
// Round 8: persistent column loop + double-buffered LDS, reg-staged async split,
//          no launch_bounds VGPR clamp (round-7 spill fix), branch-free staging.
constexpr int N_ = 64, C_ = 3, H_ = 345, W_ = 456;
constexpr int HW_ = H_ * W_;

constexpr int TW = 32, TH = 16;                // output tile: 512 px, 2 px/thread
constexpr int TX = 15, TY = 22;                // ceil(456/32), ceil(345/16)
constexpr int QS = 4;                          // column quarters per block
constexpr int CCAP = 52;                       // staged cols / LDS row stride (13 float4)
constexpr int RCAP = 28;                       // staged rows
constexpr int CH_STRIDE = RCAP * CCAP;         // 1456 floats per channel
constexpr int BUF_STRIDE = 3 * CH_STRIDE;      // 4368 floats per buffer (17472 B)
constexpr int SLOTS = (CCAP / 4) * RCAP;       // 364 float4 slots per channel

__device__ __forceinline__ void make_win(
    int w0, int h0, float Ax, float Bx, float Cx, float Ay, float By, float Cy,
    int& xa_out, int& ylo_out)
{
    float ws = (float)w0, we = (float)min(w0 + TW - 1, W_ - 1);
    float hs = (float)h0, he = (float)min(h0 + TH - 1, H_ - 1);
    float xw0 = ws * Ax, xw1 = we * Ax;
    float xh0 = hs * Bx, xh1 = he * Bx;
    float minix = Cx + fminf(xw0, xw1) + fminf(xh0, xh1);
    float maxix = Cx + fmaxf(xw0, xw1) + fmaxf(xh0, xh1);
    float yw0 = ws * Ay, yw1 = we * Ay;
    float yh0 = hs * By, yh1 = he * By;
    float miniy = Cy + fminf(yw0, yw1) + fminf(yh0, yh1);
    float maxiy = Cy + fmaxf(yw0, yw1) + fmaxf(yh0, yh1);

    int x_lo = (int)floorf(minix) - 1, x_hi = (int)floorf(maxix) + 2;
    int y_lo = (int)floorf(miniy) - 1, y_hi = (int)floorf(maxiy) + 2;

    int xa = x_lo & ~3;                        // align down (ok for negatives)
    int cols4 = (x_hi - xa + 4) >> 2;
    if (cols4 > CCAP / 4) xa += ((cols4 - CCAP / 4) >> 1) << 2;   // center oversized
    int rows = y_hi - y_lo + 1;
    if (rows > RCAP) y_lo += (rows - RCAP) >> 1;

    // clamp window fully inside the image: staging is always branch-free valid loads;
    // out-of-image corners fail the per-pixel window check -> global fallback (zeros).
    xa   = max(0, min(xa,   W_ - CCAP));       // W_-CCAP = 404, stays 4-aligned
    y_lo = max(0, min(y_lo, H_ - RCAP));
    xa_out = xa; ylo_out = y_lo;
}

__global__ __launch_bounds__(256) void gs_tiled(
    const float* __restrict__ x,      // [N,3,H,W]
    const float* __restrict__ theta,  // [N,2,3]
    float* __restrict__ out)          // [N,3,H,W]
{
    __shared__ float lds[2 * BUF_STRIDE];      // 34944 B -> 4 blocks/CU

    // XCD-affine: batch n -> XCD n%8. 3840 blocks = 8 xcd x 8 bg x (15 tx x 4 q).
    int b    = blockIdx.x;
    int xcd  = b & 7;
    int i    = b >> 3;                 // 0..479
    int bg   = i / (TX * QS);          // 0..7
    int rem  = i - bg * (TX * QS);     // 0..59
    int tx   = rem >> 2;               // 0..14
    int q    = rem & 3;                // 0..3
    int n    = xcd + 8 * bg;
    int ty0  = (q * TY) >> 2;          // {0,5,11,16}
    int ty1  = ((q + 1) * TY) >> 2;    // {5,11,16,22}
    int w0   = tx * TW;

    const float* t = theta + n * 6;
    float t00 = t[0], t01 = t[1], t02 = t[2];
    float t10 = t[3], t11 = t[4], t12 = t[5];

    const float halfW = 0.5f * (float)W_, cW = 0.5f * (float)(W_ - 1);
    const float halfH = 0.5f * (float)H_, cH = 0.5f * (float)(H_ - 1);
    const float startx = -(1.0f - 1.0f / (float)W_);
    const float starty = -(1.0f - 1.0f / (float)H_);

    // Linear map: ix = Ax*w + Bx*h + Cx ; iy = Ay*w + By*h + Cy
    float Ax = t00;
    float Bx = t01 * ((float)W_ / (float)H_);
    float Cx = fmaf(startx, t00, fmaf(starty, t01, t02)) * halfW + cW;
    float Ay = t10 * ((float)H_ / (float)W_);
    float By = t11;
    float Cy = fmaf(startx, t10, fmaf(starty, t11, t12)) * halfH + cH;

    const float* xn = x + (size_t)n * 3 * HW_;
    float* on = out + (size_t)n * 3 * HW_;

    int tid = threadIdx.x;
    // flat staging slots: slot s -> (r = s/13, j = s%13), LDS offset = 4*s floats
    int s1 = tid;
    int r1 = (s1 * 5042) >> 16;  int j1 = s1 - 13 * r1;
    int s2 = tid + 256;
    int r2 = (s2 * 5042) >> 16;  int j2 = s2 - 13 * r2;
    bool has2 = (s2 < SLOTS);                  // tid < 108
    const float* base1 = xn + r1 * W_ + 4 * j1;
    const float* base2 = xn + r2 * W_ + 4 * j2;

    int tw = (tid & 15) * 2, th = tid >> 4;

    float4 p0, p1, p2, q0, q1, q2;

    // prologue: stage first tile (latency exposed once per block)
    int cxa, cylo;
    make_win(w0, ty0 * TH, Ax, Bx, Cx, Ay, By, Cy, cxa, cylo);
    {
        const float* g1 = base1 + cylo * W_ + cxa;
        p0 = *(const float4*)(g1);
        p1 = *(const float4*)(g1 + HW_);
        p2 = *(const float4*)(g1 + 2 * HW_);
        if (has2) {
            const float* g2 = base2 + cylo * W_ + cxa;
            q0 = *(const float4*)(g2);
            q1 = *(const float4*)(g2 + HW_);
            q2 = *(const float4*)(g2 + 2 * HW_);
        }
        float* d1 = lds + 4 * s1;
        *(float4*)(d1)                 = p0;
        *(float4*)(d1 + CH_STRIDE)     = p1;
        *(float4*)(d1 + 2 * CH_STRIDE) = p2;
        if (has2) {
            float* d2 = lds + 4 * s2;
            *(float4*)(d2)                 = q0;
            *(float4*)(d2 + CH_STRIDE)     = q1;
            *(float4*)(d2 + 2 * CH_STRIDE) = q2;
        }
    }
    __syncthreads();

    int cur = 0;
    for (int k = ty0; k < ty1; ++k) {
        bool hn = (k + 1) < ty1;
        int nxa = 0, nylo = 0;
        if (hn) {
            // issue next tile's loads early: latency hides under compute below
            make_win(w0, (k + 1) * TH, Ax, Bx, Cx, Ay, By, Cy, nxa, nylo);
            const float* g1 = base1 + nylo * W_ + nxa;
            p0 = *(const float4*)(g1);
            p1 = *(const float4*)(g1 + HW_);
            p2 = *(const float4*)(g1 + 2 * HW_);
            if (has2) {
                const float* g2 = base2 + nylo * W_ + nxa;
                q0 = *(const float4*)(g2);
                q1 = *(const float4*)(g2 + HW_);
                q2 = *(const float4*)(g2 + 2 * HW_);
            }
        }

        // ---- compute tile k from buffer `cur` ----
        const float* B = lds + cur * BUF_STRIDE;
        int h = k * TH + th;
        int w = w0 + tw;
        if (w < W_ && h < H_) {
            float fw = (float)w, fh = (float)h;
            float hx  = fmaf(fh, Bx, Cx), hy = fmaf(fh, By, Cy);
            float ixA = fmaf(fw, Ax, hx), iyA = fmaf(fw, Ay, hy);
            float ixB = ixA + Ax,         iyB = iyA + Ay;

            float xfA = floorf(ixA), yfA = floorf(iyA);
            float fxA = ixA - xfA,   fyA = iyA - yfA;
            int   XA  = (int)xfA,    YA  = (int)yfA;

            float xfB = floorf(ixB), yfB = floorf(iyB);
            float fxB = ixB - xfB,   fyB = iyB - yfB;
            int   XB  = (int)xfB,    YB  = (int)yfB;

            int lcA = XA - cxa, lrA = YA - cylo;
            int lcB = XB - cxa, lrB = YB - cylo;
            bool inA = (unsigned)lcA < (unsigned)(CCAP - 1) && (unsigned)lrA < (unsigned)(RCAP - 1);
            bool inB = (unsigned)lcB < (unsigned)(CCAP - 1) && (unsigned)lrB < (unsigned)(RCAP - 1);

            float vA0, vA1, vA2, vB0, vB1, vB2;

            if (__builtin_expect(inA & inB, 1)) {
                const float* pA = B + lrA * CCAP + lcA;
                const float* pB = B + lrB * CCAP + lcB;
                {
                    float a00 = pA[0], a10 = pA[1], a01 = pA[CCAP], a11 = pA[CCAP + 1];
                    float b00 = pB[0], b10 = pB[1], b01 = pB[CCAP], b11 = pB[CCAP + 1];
                    float at = fmaf(fxA, a10 - a00, a00), ab = fmaf(fxA, a11 - a01, a01);
                    float bt = fmaf(fxB, b10 - b00, b00), bb = fmaf(fxB, b11 - b01, b01);
                    vA0 = fmaf(fyA, ab - at, at);
                    vB0 = fmaf(fyB, bb - bt, bt);
                }
                {
                    float a00 = pA[CH_STRIDE], a10 = pA[CH_STRIDE + 1];
                    float a01 = pA[CH_STRIDE + CCAP], a11 = pA[CH_STRIDE + CCAP + 1];
                    float b00 = pB[CH_STRIDE], b10 = pB[CH_STRIDE + 1];
                    float b01 = pB[CH_STRIDE + CCAP], b11 = pB[CH_STRIDE + CCAP + 1];
                    float at = fmaf(fxA, a10 - a00, a00), ab = fmaf(fxA, a11 - a01, a01);
                    float bt = fmaf(fxB, b10 - b00, b00), bb = fmaf(fxB, b11 - b01, b01);
                    vA1 = fmaf(fyA, ab - at, at);
                    vB1 = fmaf(fyB, bb - bt, bt);
                }
                {
                    float a00 = pA[2 * CH_STRIDE], a10 = pA[2 * CH_STRIDE + 1];
                    float a01 = pA[2 * CH_STRIDE + CCAP], a11 = pA[2 * CH_STRIDE + CCAP + 1];
                    float b00 = pB[2 * CH_STRIDE], b10 = pB[2 * CH_STRIDE + 1];
                    float b01 = pB[2 * CH_STRIDE + CCAP], b11 = pB[2 * CH_STRIDE + CCAP + 1];
                    float at = fmaf(fxA, a10 - a00, a00), ab = fmaf(fxA, a11 - a01, a01);
                    float bt = fmaf(fxB, b10 - b00, b00), bb = fmaf(fxB, b11 - b01, b01);
                    vA2 = fmaf(fyA, ab - at, at);
                    vB2 = fmaf(fyB, bb - bt, bt);
                }
            } else {
                // corner(s) outside staged window (incl. out-of-image): direct gather
                float gxA = 1.0f - fxA, gyA = 1.0f - fyA;
                float gxB = 1.0f - fxB, gyB = 1.0f - fyB;
                float wA00 = gxA * gyA, wA10 = fxA * gyA, wA01 = gxA * fyA, wA11 = fxA * fyA;
                float wB00 = gxB * gyB, wB10 = fxB * gyB, wB01 = gxB * fyB, wB11 = fxB * fyB;
                vA0 = vA1 = vA2 = vB0 = vB1 = vB2 = 0.0f;
#define CORNG(xi, yi, wt, d0, d1, d2)                                         \
                if ((unsigned)(xi) < (unsigned)W_ && (unsigned)(yi) < (unsigned)H_) { \
                    int off = (yi) * W_ + (xi);                               \
                    d0 += xn[off] * (wt);                                     \
                    d1 += xn[HW_ + off] * (wt);                               \
                    d2 += xn[2 * HW_ + off] * (wt);                           \
                }
                CORNG(XA,     YA,     wA00, vA0, vA1, vA2)
                CORNG(XA + 1, YA,     wA10, vA0, vA1, vA2)
                CORNG(XA,     YA + 1, wA01, vA0, vA1, vA2)
                CORNG(XA + 1, YA + 1, wA11, vA0, vA1, vA2)
                CORNG(XB,     YB,     wB00, vB0, vB1, vB2)
                CORNG(XB + 1, YB,     wB10, vB0, vB1, vB2)
                CORNG(XB,     YB + 1, wB01, vB0, vB1, vB2)
                CORNG(XB + 1, YB + 1, wB11, vB0, vB1, vB2)
#undef CORNG
            }

            size_t o = (size_t)h * W_ + w;
            *(float2*)(on + o)           = make_float2(vA0, vB0);
            *(float2*)(on + o + HW_)     = make_float2(vA1, vB1);
            *(float2*)(on + o + 2 * HW_) = make_float2(vA2, vB2);
        }

        // ---- write next tile into the other buffer (loads have drained by now) ----
        if (hn) {
            float* d1 = lds + (cur ^ 1) * BUF_STRIDE + 4 * s1;
            *(float4*)(d1)                 = p0;
            *(float4*)(d1 + CH_STRIDE)     = p1;
            *(float4*)(d1 + 2 * CH_STRIDE) = p2;
            if (has2) {
                float* d2 = lds + (cur ^ 1) * BUF_STRIDE + 4 * s2;
                *(float4*)(d2)                 = q0;
                *(float4*)(d2 + CH_STRIDE)     = q1;
                *(float4*)(d2 + 2 * CH_STRIDE) = q2;
            }
            cxa = nxa; cylo = nylo;
        }
        __syncthreads();                       // new buffer visible; old buffer free
        cur ^= 1;
    }
}

extern "C" void kernel_launch(void* const* d_in, const int* in_sizes, int n_in,
                              void* d_out, int out_size, void* d_ws, size_t ws_size,
                              hipStream_t stream) {
    const float* x     = (const float*)d_in[0];
    const float* theta = (const float*)d_in[1];
    float* out = (float*)d_out;

    int blocks = N_ * TX * QS;   // 3840, divisible by 8
    gs_tiled<<<blocks, 256, 0, stream>>>(x, theta, out);
}

// Round 9
// 44.312 us; speedup vs baseline: 3.0692x; 1.2287x over previous
//
#include <hip/hip_runtime.h>

// affine_grid + grid_sample (bilinear, zeros, align_corners=False)
// N=64, C=3, H=345, W=456, fp32.
// Round 9: round-6 geometry (1 tile/block, 17.5KB LDS, 8 blocks/CU, grid 21120)
//          + round-8 branch-free clamped staging (flat float4 slots)
//          + packed f32x2 interpolation for the A/B pixel pair.
constexpr int N_ = 64, C_ = 3, H_ = 345, W_ = 456;
constexpr int HW_ = H_ * W_;

constexpr int TW = 32, TH = 16;                // output tile: 512 px, 2 px/thread
constexpr int TX = 15, TY = 22;                // ceil(456/32), ceil(345/16)
constexpr int TILES = TX * TY;                 // 330
constexpr int CCAP = 52;                       // staged cols / LDS row stride (13 float4)
constexpr int RCAP = 28;                       // staged rows
constexpr int CH_STRIDE = RCAP * CCAP;         // 1456 floats per channel (17472 B total)
constexpr int SLOTS = (CCAP / 4) * RCAP;       // 364 float4 slots per channel

typedef __attribute__((ext_vector_type(2))) float f32x2;

__device__ __forceinline__ void make_win(
    int w0, int h0, float Ax, float Bx, float Cx, float Ay, float By, float Cy,
    int& xa_out, int& ylo_out)
{
    float ws = (float)w0, we = (float)min(w0 + TW - 1, W_ - 1);
    float hs = (float)h0, he = (float)min(h0 + TH - 1, H_ - 1);
    float xw0 = ws * Ax, xw1 = we * Ax;
    float xh0 = hs * Bx, xh1 = he * Bx;
    float minix = Cx + fminf(xw0, xw1) + fminf(xh0, xh1);
    float maxix = Cx + fmaxf(xw0, xw1) + fmaxf(xh0, xh1);
    float yw0 = ws * Ay, yw1 = we * Ay;
    float yh0 = hs * By, yh1 = he * By;
    float miniy = Cy + fminf(yw0, yw1) + fminf(yh0, yh1);
    float maxiy = Cy + fmaxf(yw0, yw1) + fmaxf(yh0, yh1);

    int x_lo = (int)floorf(minix) - 1, x_hi = (int)floorf(maxix) + 2;
    int y_lo = (int)floorf(miniy) - 1, y_hi = (int)floorf(maxiy) + 2;

    int xa = x_lo & ~3;                        // align down (ok for negatives)
    int cols4 = (x_hi - xa + 4) >> 2;
    if (cols4 > CCAP / 4) xa += ((cols4 - CCAP / 4) >> 1) << 2;   // center oversized
    int rows = y_hi - y_lo + 1;
    if (rows > RCAP) y_lo += (rows - RCAP) >> 1;

    // clamp fully inside image: staging is branch-free valid float4 loads;
    // pixels whose corners leave the window use the per-pixel global fallback.
    xa   = max(0, min(xa,   W_ - CCAP));       // W_-CCAP = 404 (4-aligned)
    y_lo = max(0, min(y_lo, H_ - RCAP));
    xa_out = xa; ylo_out = y_lo;
}

__global__ __launch_bounds__(256) void gs_tiled(
    const float* __restrict__ x,      // [N,3,H,W]
    const float* __restrict__ theta,  // [N,2,3]
    float* __restrict__ out)          // [N,3,H,W]
{
    __shared__ float lds[3 * CH_STRIDE];       // 17472 B -> 8 blocks/CU

    // XCD-affine: batch n -> XCD n%8 only (grid divisible by 8).
    int b    = blockIdx.x;
    int xcd  = b & 7;
    int i    = b >> 3;
    int bg   = i / TILES;
    int tile = i - bg * TILES;
    int n    = xcd + 8 * bg;

    int ty = tile / TX;
    int tx = tile - ty * TX;
    int w0 = tx * TW, h0 = ty * TH;

    const float* t = theta + n * 6;
    float t00 = t[0], t01 = t[1], t02 = t[2];
    float t10 = t[3], t11 = t[4], t12 = t[5];

    const float halfW = 0.5f * (float)W_, cW = 0.5f * (float)(W_ - 1);
    const float halfH = 0.5f * (float)H_, cH = 0.5f * (float)(H_ - 1);
    const float startx = -(1.0f - 1.0f / (float)W_);
    const float starty = -(1.0f - 1.0f / (float)H_);

    // Linear map: ix = Ax*w + Bx*h + Cx ; iy = Ay*w + By*h + Cy
    float Ax = t00;
    float Bx = t01 * ((float)W_ / (float)H_);
    float Cx = fmaf(startx, t00, fmaf(starty, t01, t02)) * halfW + cW;
    float Ay = t10 * ((float)H_ / (float)W_);
    float By = t11;
    float Cy = fmaf(startx, t10, fmaf(starty, t11, t12)) * halfH + cH;

    const float* xn = x + (size_t)n * 3 * HW_;
    float* on = out + (size_t)n * 3 * HW_;

    int tid = threadIdx.x;

    int cxa, cylo;
    make_win(w0, h0, Ax, Bx, Cx, Ay, By, Cy, cxa, cylo);

    // ---- branch-free staging: flat float4 slots, window always inside image ----
    {
        int s1 = tid;
        int r1 = s1 / 13, j1 = s1 - 13 * r1;
        const float* g1 = xn + (size_t)(cylo + r1) * W_ + cxa + 4 * j1;
        float4 a0 = *(const float4*)(g1);
        float4 a1 = *(const float4*)(g1 + HW_);
        float4 a2 = *(const float4*)(g1 + 2 * HW_);
        float* d1 = lds + 4 * s1;
        *(float4*)(d1)                 = a0;
        *(float4*)(d1 + CH_STRIDE)     = a1;
        *(float4*)(d1 + 2 * CH_STRIDE) = a2;

        int s2 = tid + 256;
        if (s2 < SLOTS) {                      // tid < 108
            int r2 = s2 / 13, j2 = s2 - 13 * r2;
            const float* g2 = xn + (size_t)(cylo + r2) * W_ + cxa + 4 * j2;
            float4 b0 = *(const float4*)(g2);
            float4 b1 = *(const float4*)(g2 + HW_);
            float4 b2 = *(const float4*)(g2 + 2 * HW_);
            float* d2 = lds + 4 * s2;
            *(float4*)(d2)                 = b0;
            *(float4*)(d2 + CH_STRIDE)     = b1;
            *(float4*)(d2 + 2 * CH_STRIDE) = b2;
        }
    }
    __syncthreads();

    // ---- compute: 2 consecutive-w px/thread, packed f32x2 interpolation ----
    int tw = (tid & 15) * 2, th = tid >> 4;
    int w = w0 + tw, h = h0 + th;
    if (w >= W_ || h >= H_) return;            // after the only barrier

    float fw = (float)w, fh = (float)h;
    float hx  = fmaf(fh, Bx, Cx), hy = fmaf(fh, By, Cy);
    float ixA = fmaf(fw, Ax, hx), iyA = fmaf(fw, Ay, hy);
    float ixB = ixA + Ax,         iyB = iyA + Ay;

    float xfA = floorf(ixA), yfA = floorf(iyA);
    float fxA = ixA - xfA,   fyA = iyA - yfA;
    int   XA  = (int)xfA,    YA  = (int)yfA;

    float xfB = floorf(ixB), yfB = floorf(iyB);
    float fxB = ixB - xfB,   fyB = iyB - yfB;
    int   XB  = (int)xfB,    YB  = (int)yfB;

    int lcA = XA - cxa, lrA = YA - cylo;
    int lcB = XB - cxa, lrB = YB - cylo;
    bool inA = (unsigned)lcA < (unsigned)(CCAP - 1) && (unsigned)lrA < (unsigned)(RCAP - 1);
    bool inB = (unsigned)lcB < (unsigned)(CCAP - 1) && (unsigned)lrB < (unsigned)(RCAP - 1);

    size_t o = (size_t)h * W_ + w;

    if (__builtin_expect(inA & inB, 1)) {
        const float* pA = lds + lrA * CCAP + lcA;
        const float* pB = lds + lrB * CCAP + lcB;
        f32x2 FX = {fxA, fxB};
        f32x2 FY = {fyA, fyB};

        // channel 0
        {
            f32x2 P00 = {pA[0],        pB[0]};
            f32x2 P10 = {pA[1],        pB[1]};
            f32x2 P01 = {pA[CCAP],     pB[CCAP]};
            f32x2 P11 = {pA[CCAP + 1], pB[CCAP + 1]};
            f32x2 top = (P10 - P00) * FX + P00;
            f32x2 bot = (P11 - P01) * FX + P01;
            f32x2 v   = (bot - top) * FY + top;
            *(float2*)(on + o) = make_float2(v.x, v.y);
        }
        // channel 1
        {
            f32x2 P00 = {pA[CH_STRIDE],            pB[CH_STRIDE]};
            f32x2 P10 = {pA[CH_STRIDE + 1],        pB[CH_STRIDE + 1]};
            f32x2 P01 = {pA[CH_STRIDE + CCAP],     pB[CH_STRIDE + CCAP]};
            f32x2 P11 = {pA[CH_STRIDE + CCAP + 1], pB[CH_STRIDE + CCAP + 1]};
            f32x2 top = (P10 - P00) * FX + P00;
            f32x2 bot = (P11 - P01) * FX + P01;
            f32x2 v   = (bot - top) * FY + top;
            *(float2*)(on + o + HW_) = make_float2(v.x, v.y);
        }
        // channel 2
        {
            f32x2 P00 = {pA[2 * CH_STRIDE],            pB[2 * CH_STRIDE]};
            f32x2 P10 = {pA[2 * CH_STRIDE + 1],        pB[2 * CH_STRIDE + 1]};
            f32x2 P01 = {pA[2 * CH_STRIDE + CCAP],     pB[2 * CH_STRIDE + CCAP]};
            f32x2 P11 = {pA[2 * CH_STRIDE + CCAP + 1], pB[2 * CH_STRIDE + CCAP + 1]};
            f32x2 top = (P10 - P00) * FX + P00;
            f32x2 bot = (P11 - P01) * FX + P01;
            f32x2 v   = (bot - top) * FY + top;
            *(float2*)(on + o + 2 * HW_) = make_float2(v.x, v.y);
        }
    } else {
        // rare: corner(s) outside staged window (incl. out-of-image): direct gather
        float gxA = 1.0f - fxA, gyA = 1.0f - fyA;
        float gxB = 1.0f - fxB, gyB = 1.0f - fyB;
        float wA00 = gxA * gyA, wA10 = fxA * gyA, wA01 = gxA * fyA, wA11 = fxA * fyA;
        float wB00 = gxB * gyB, wB10 = fxB * gyB, wB01 = gxB * fyB, wB11 = fxB * fyB;
        float vA0 = 0, vA1 = 0, vA2 = 0, vB0 = 0, vB1 = 0, vB2 = 0;
#define CORNG(xi, yi, wt, d0, d1, d2)                                         \
        if ((unsigned)(xi) < (unsigned)W_ && (unsigned)(yi) < (unsigned)H_) { \
            int off = (yi) * W_ + (xi);                                       \
            d0 += xn[off] * (wt);                                             \
            d1 += xn[HW_ + off] * (wt);                                       \
            d2 += xn[2 * HW_ + off] * (wt);                                   \
        }
        CORNG(XA,     YA,     wA00, vA0, vA1, vA2)
        CORNG(XA + 1, YA,     wA10, vA0, vA1, vA2)
        CORNG(XA,     YA + 1, wA01, vA0, vA1, vA2)
        CORNG(XA + 1, YA + 1, wA11, vA0, vA1, vA2)
        CORNG(XB,     YB,     wB00, vB0, vB1, vB2)
        CORNG(XB + 1, YB,     wB10, vB0, vB1, vB2)
        CORNG(XB,     YB + 1, wB01, vB0, vB1, vB2)
        CORNG(XB + 1, YB + 1, wB11, vB0, vB1, vB2)
#undef CORNG
        *(float2*)(on + o)           = make_float2(vA0, vB0);
        *(float2*)(on + o + HW_)     = make_float2(vA1, vB1);
        *(float2*)(on + o + 2 * HW_) = make_float2(vA2, vB2);
    }
}

extern "C" void kernel_launch(void* const* d_in, const int* in_sizes, int n_in,
                              void* d_out, int out_size, void* d_ws, size_t ws_size,
                              hipStream_t stream) {
    const float* x     = (const float*)d_in[0];
    const float* theta = (const float*)d_in[1];
    float* out = (float*)d_out;

    int blocks = N_ * TILES;   // 21120, divisible by 8
    gs_tiled<<<blocks, 256, 0, stream>>>(x, theta, out);
}